// Round 5
// baseline (3434.701 us; speedup 1.0000x reference)
//
#include <hip/hip_runtime.h>
#include <cstdint>

// LSTM fused kernel for MI355X — round 7: MFMA-batched recurrence.
// Main path: 4 blocks x 512 threads; each block advances 16 batches per step
// with v_mfma_i32_16x16x64_i8 (16x1024x256 int8 GEMM per timestep, weights
// resident as B-fragments, h int8 in XOR-swizzled LDS A-buffer). N-columns are
// pre-permuted so each thread's 32 accumulator elems = 4 gates x 2 rows x 4
// batches -> in-lane nonlinearity. x-contribution precomputed (xg, f16,
// thread-arranged); fc deferred to a post GEMM over an h-f16 history.
// ws needs 344MB; if ws_size is smaller, falls back to the verified round-6
// kernel (3410us).

#define B_  64
#define T_  2048
#define I_  32
#define H_  256
#define O_  32
#define MB  16     // batches per block (main path)
#define NBLK 4

typedef int v4i __attribute__((ext_vector_type(4)));
typedef unsigned int v4u __attribute__((ext_vector_type(4)));
typedef _Float16 h2_t __attribute__((ext_vector_type(2)));

#if __has_builtin(__builtin_amdgcn_sdot4)
__device__ __forceinline__ int dot4(int a, int b, int c) {
    return __builtin_amdgcn_sdot4(a, b, c, false);
}
#else
__device__ __forceinline__ int dot4(int a, int b, int c) {
    c += (int)(int8_t)(a)        * (int)(int8_t)(b);
    c += (int)(int8_t)(a >> 8)   * (int)(int8_t)(b >> 8);
    c += (int)(int8_t)(a >> 16)  * (int)(int8_t)(b >> 16);
    c += (int)(int8_t)(a >> 24)  * (int)(int8_t)(b >> 24);
    return c;
}
#endif

__device__ __forceinline__ float fdot2h(h2_t a, h2_t b, float c) {
#if __has_builtin(__builtin_amdgcn_fdot2)
    return __builtin_amdgcn_fdot2(a, b, c, false);
#else
    return c + (float)a[0] * (float)b[0] + (float)a[1] * (float)b[1];
#endif
}

// ---- DPP reductions ----
__device__ __forceinline__ float wave64_max_bcast(float v) {
    int t;
    t = __builtin_amdgcn_update_dpp(__float_as_int(v), __float_as_int(v), 0x111, 0xf, 0xf, false);
    v = fmaxf(v, __int_as_float(t));
    t = __builtin_amdgcn_update_dpp(__float_as_int(v), __float_as_int(v), 0x112, 0xf, 0xf, false);
    v = fmaxf(v, __int_as_float(t));
    t = __builtin_amdgcn_update_dpp(__float_as_int(v), __float_as_int(v), 0x114, 0xf, 0xf, false);
    v = fmaxf(v, __int_as_float(t));
    t = __builtin_amdgcn_update_dpp(__float_as_int(v), __float_as_int(v), 0x118, 0xf, 0xf, false);
    v = fmaxf(v, __int_as_float(t));
    t = __builtin_amdgcn_update_dpp(__float_as_int(v), __float_as_int(v), 0x142, 0xa, 0xf, false);
    v = fmaxf(v, __int_as_float(t));
    t = __builtin_amdgcn_update_dpp(__float_as_int(v), __float_as_int(v), 0x143, 0xc, 0xf, false);
    v = fmaxf(v, __int_as_float(t));
    return __int_as_float(__builtin_amdgcn_readlane(__float_as_int(v), 63));
}

// sum over each group of 8 consecutive lanes; lane (8k+7) holds its group sum.
__device__ __forceinline__ float sum8(float v) {
    int t;
    t = __builtin_amdgcn_update_dpp(0, __float_as_int(v), 0x111, 0xf, 0xf, true); v += __int_as_float(t);
    t = __builtin_amdgcn_update_dpp(0, __float_as_int(v), 0x112, 0xf, 0xf, true); v += __int_as_float(t);
    t = __builtin_amdgcn_update_dpp(0, __float_as_int(v), 0x114, 0xf, 0xf, true); v += __int_as_float(t);
    return v;
}

// max over each 16-lane DPP row via row_shr; lane (16k+15) holds row max.
__device__ __forceinline__ float row16_max(float v) {
    int t;
    t = __builtin_amdgcn_update_dpp(__float_as_int(v), __float_as_int(v), 0x111, 0xf, 0xf, false);
    v = fmaxf(v, __int_as_float(t));
    t = __builtin_amdgcn_update_dpp(__float_as_int(v), __float_as_int(v), 0x112, 0xf, 0xf, false);
    v = fmaxf(v, __int_as_float(t));
    t = __builtin_amdgcn_update_dpp(__float_as_int(v), __float_as_int(v), 0x114, 0xf, 0xf, false);
    v = fmaxf(v, __int_as_float(t));
    t = __builtin_amdgcn_update_dpp(__float_as_int(v), __float_as_int(v), 0x118, 0xf, 0xf, false);
    v = fmaxf(v, __int_as_float(t));
    return v;
}

// ---------------- ws layout ----------------
// main path:
#define WQ_OFF    0           // 256KB  int8 Wq' [1024 c][64 dw] (c-permuted)
#define S1_OFF    262144      // 4KB    f32 s1p[c]
#define BIAS_OFF  266240      // 4KB    f32 biasp[c]
#define WIHH_OFF  270336      // 64KB   f16 wihh[c][16 dw]
#define XH_OFF    335872      // 8MB    f16 x            (shared w/ fallback)
#define XGA_OFF   8724480     // 256MB  f16 xg arranged
#define HIST_OFF  277159936   // 64MB   f16 h history [b][t][r]
#define WS_NEED   344268800ULL
// fallback (round-6) path:
#define FQW_OFF   0
#define FWIH_OFF  262144
#define FS1_OFF   327680
#define FBIAS_OFF 331776

__device__ __forceinline__ uint32_t pack_q(int q0, int q1, int q2, int q3) {
    return  ((uint32_t)(uint8_t)(int8_t)q0)
          | (((uint32_t)(uint8_t)(int8_t)q1) << 8)
          | (((uint32_t)(uint8_t)(int8_t)q2) << 16)
          | (((uint32_t)(uint8_t)(int8_t)q3) << 24);
}

__device__ __forceinline__ int clamp127(int v) {
    return v < -127 ? -127 : (v > 127 ? 127 : v);
}

// ======================= shared prep: x -> f16 =======================
__global__ __launch_bounds__(256) void prep_xh(
    const float* __restrict__ x, uint32_t* __restrict__ xh)
{
    const int i = blockIdx.x * 256 + threadIdx.x;   // dword index < B*T*16
    const float2 v = ((const float2*)x)[i];
    union { uint32_t u; h2_t h; } z;
    z.h[0] = (_Float16)v.x; z.h[1] = (_Float16)v.y;
    xh[i] = z.u;
}

// ======================= main path preps =======================
// prep_wq: quantize Whh (int8, per-gate-row scale) into the c-permuted layout
// c = ((r>>4)<<6) | (g<<4) | (r&15);  grid 1024 blocks x 64 thr.
__global__ __launch_bounds__(64) void prep_wq(
    const float* __restrict__ Whh, const float* __restrict__ Wih,
    const float* __restrict__ bih, const float* __restrict__ bhh,
    uint32_t* __restrict__ wq, float* __restrict__ s1p,
    float* __restrict__ biasp, uint32_t* __restrict__ wihh)
{
    const int gr = blockIdx.x;
    const int j  = threadIdx.x;
    const int g  = gr >> 8, r = gr & 255;
    const int c  = ((r >> 4) << 6) | (g << 4) | (r & 15);

    const float4 wv = ((const float4*)(Whh + gr * H_))[j];
    float m = fmaxf(fmaxf(fabsf(wv.x), fabsf(wv.y)), fmaxf(fabsf(wv.z), fabsf(wv.w)));
    #pragma unroll
    for (int s = 1; s < 64; s <<= 1) m = fmaxf(m, __shfl_xor(m, s, 64));
    const float S1 = fmaxf(m, 1e-20f) / 127.f;
    const float r1 = 1.f / S1;
    wq[c * 64 + j] = pack_q(
        clamp127((int)rintf(wv.x * r1)), clamp127((int)rintf(wv.y * r1)),
        clamp127((int)rintf(wv.z * r1)), clamp127((int)rintf(wv.w * r1)));
    if (j < 16) {
        union { uint32_t u; h2_t h; } z;
        z.h[0] = (_Float16)Wih[gr * I_ + 2 * j];
        z.h[1] = (_Float16)Wih[gr * I_ + 2 * j + 1];
        wihh[c * 16 + j] = z.u;
    }
    if (j == 0) { s1p[c] = S1; biasp[c] = bih[gr] + bhh[gr]; }
}

// prep_xg: xg[b,t,c] = x[b,t,:] . Wih'[c,:] + bias[c], f16, arranged so main's
// thread tid reads its 32 values (reg,nt) as 16 consecutive dwords.
// grid = NBLK*T blocks x 512 thr; blockIdx = blk*2048 + t.
__global__ __launch_bounds__(512) void prep_xg(
    const uint32_t* __restrict__ xh, const uint32_t* __restrict__ wihh,
    const float* __restrict__ biasp, uint32_t* __restrict__ xga)
{
    const int bx = blockIdx.x;
    const int blk = bx >> 11, t = bx & 2047;
    const int tid = threadIdx.x;
    const int wv = tid >> 6, l = tid & 63, lq = l >> 4, lo = l & 15;

    uint32_t outw[16];
    #pragma unroll
    for (int reg = 0; reg < 4; reg++) {
        const int b = blk * MB + lq * 4 + reg;
        const uint32_t* xr = xh + ((size_t)b * T_ + t) * 16;
        uint32_t xd[16];
        #pragma unroll
        for (int d = 0; d < 16; d++) xd[d] = xr[d];
        #pragma unroll
        for (int np = 0; np < 4; np++) {
            float acc2[2];
            #pragma unroll
            for (int hh = 0; hh < 2; hh++) {
                const int nt = np * 2 + hh;
                const int c = wv * 128 + nt * 16 + lo;
                const uint32_t* wr = wihh + c * 16;
                float acc = biasp[c];
                #pragma unroll
                for (int d = 0; d < 16; d++) {
                    union { uint32_t u; h2_t h; } zw, zx;
                    zw.u = wr[d]; zx.u = xd[d];
                    acc = fdot2h(zw.h, zx.h, acc);
                }
                acc2[hh] = acc;
            }
            union { uint32_t u; h2_t h; } zo;
            zo.h[0] = (_Float16)acc2[0]; zo.h[1] = (_Float16)acc2[1];
            outw[reg * 4 + np] = zo.u;
        }
    }
    uint32_t* dst = xga + ((size_t)bx * 512 + tid) * 16;
    #pragma unroll
    for (int d = 0; d < 16; d++) dst[d] = outw[d];
}

// ======================= main: MFMA recurrence =======================
// 4 blocks x 512 thr (8 waves, 2/SIMD). Wave wv owns N-cols [wv*128,wv*128+128).
// C/D layout (verified m89): col = lane&15, row(batch) = (lane>>4)*4 + reg.
// A/B frags: row/col = lane&15, 16 k-bytes per lane (k-quarter = lane>>4;
// k-order inside frags cancels between A and B).
__global__ __launch_bounds__(512, 2) void lstm_mfma(
    const uint32_t* __restrict__ wq, const float* __restrict__ s1p,
    const uint32_t* __restrict__ xga, _Float16* __restrict__ hist)
{
    const int blk = blockIdx.x;
    const int tid = threadIdx.x;
    const int wv = tid >> 6, l = tid & 63, lq = l >> 4, lo = l & 15;

    __shared__ char  Ab[2][4096];     // h int8 [16 b][256 k], chunk-swizzled
    __shared__ int   shmax[2][16];    // per-batch |h| max (int-punned f32)
    __shared__ float shsc[2][16];     // per-batch dequant scale

    // resident B fragments + column scales
    v4i  wB[8][4];
    float s1c[8];
    #pragma unroll
    for (int nt = 0; nt < 8; nt++) {
        const int c = wv * 128 + nt * 16 + lo;
        s1c[nt] = s1p[c];
        #pragma unroll
        for (int kt = 0; kt < 4; kt++)
            wB[nt][kt] = *(const v4i*)(wq + (size_t)c * 64 + kt * 16 + lq * 4);
    }

    {   // init: zero Ab[0] (h(0)=0), shmax both, shsc[0]
        uint32_t* a0 = (uint32_t*)&Ab[0][0];
        a0[tid] = 0; a0[tid + 512] = 0;
        if (tid < 16) { shmax[0][tid] = 0; shmax[1][tid] = 0; shsc[0][tid] = 0.f; }
    }
    __syncthreads();

    float cst[4][2];
    #pragma unroll
    for (int reg = 0; reg < 4; reg++) { cst[reg][0] = 0.f; cst[reg][1] = 0.f; }

    // per-thread hist base offsets (8 rows: 4 batches x 2 h-rows)
    size_t hbase[4][2];
    #pragma unroll
    for (int reg = 0; reg < 4; reg++)
        #pragma unroll
        for (int rr = 0; rr < 2; rr++)
            hbase[reg][rr] = ((size_t)(blk * MB + lq * 4 + reg) * T_) * 256
                           + (size_t)(wv * 32 + rr * 16 + lo);

    const uint32_t* xgb = xga + (size_t)blk * T_ * 8192 + (size_t)tid * 16;

    // preload xg for t=0
    v4u xgv[4];
    {
        const v4u* xp = (const v4u*)xgb;
        xgv[0] = xp[0]; xgv[1] = xp[1]; xgv[2] = xp[2]; xgv[3] = xp[3];
    }

    for (int t = 0; t < T_; t++) {
        const int rb = t & 1, wb = rb ^ 1;

        // prev-step h scales
        float shp[4];
        #pragma unroll
        for (int reg = 0; reg < 4; reg++) shp[reg] = shsc[rb][lq * 4 + reg];

        // A fragments (swizzled chunks: chunk' = (kt*4+lq) ^ row)
        v4i af[4];
        #pragma unroll
        for (int kt = 0; kt < 4; kt++)
            af[kt] = *(const v4i*)&Ab[rb][lo * 256 + (((kt * 4 + lq) ^ lo) << 4)];

        // GEMM: 16 batches x 128 cols (this wave) x K=256
        v4i C[8];
        #pragma unroll
        for (int nt = 0; nt < 8; nt++) {
            v4i acc = {0, 0, 0, 0};
            #pragma unroll
            for (int kt = 0; kt < 4; kt++)
                acc = __builtin_amdgcn_mfma_i32_16x16x64_i8(af[kt], wB[nt][kt], acc, 0, 0, 0);
            C[nt] = acc;
        }

        // epilogue + nonlinearity, fully in-lane
        float hv[4][2];
        #pragma unroll
        for (int reg = 0; reg < 4; reg++) {
            const float sp = shp[reg];
            #pragma unroll
            for (int rr = 0; rr < 2; rr++) {
                float ga[4];
                #pragma unroll
                for (int g = 0; g < 4; g++) {
                    const int nt = rr * 4 + g;
                    const int d  = reg * 4 + (nt >> 1);
                    const uint32_t u = xgv[d >> 2][d & 3] >> (16 * (nt & 1));
                    union { unsigned short s; _Float16 h; } ux;
                    ux.s = (unsigned short)(u & 0xffffu);
                    ga[g] = fmaf((float)C[nt][reg], s1c[nt] * sp, (float)ux.h);
                }
                const float i_ = 1.f / (1.f + __expf(-ga[0]));
                const float f_ = 1.f / (1.f + __expf(-ga[1]));
                const float g_ = 2.f / (1.f + __expf(-2.f * ga[2])) - 1.f;
                const float o_ = 1.f / (1.f + __expf(-ga[3]));
                const float cs = f_ * cst[reg][rr] + i_ * g_;
                cst[reg][rr] = cs;
                const float tc = 2.f / (1.f + __expf(-2.f * cs)) - 1.f;
                const float h = o_ * tc;
                hv[reg][rr] = h;
                hist[hbase[reg][rr] + (size_t)t * 256] = (_Float16)h;   // fire & forget
            }
        }

        // prefetch xg for t+1 (regs free after epilogue)
        {
            const int tn = (t + 1 < T_) ? (t + 1) : t;
            const v4u* xp = (const v4u*)(xgb + (size_t)tn * 8192);
            xgv[0] = xp[0]; xgv[1] = xp[1]; xgv[2] = xp[2]; xgv[3] = xp[3];
        }

        // per-batch |h| max: row16 DPP reduce, one atomic per 16-lane row
        #pragma unroll
        for (int reg = 0; reg < 4; reg++) {
            float vm = fmaxf(fabsf(hv[reg][0]), fabsf(hv[reg][1]));
            vm = row16_max(vm);
            if (lo == 15) atomicMax(&shmax[wb][lq * 4 + reg], __float_as_int(vm));
        }

        asm volatile("s_waitcnt lgkmcnt(0)" ::: "memory");
        __builtin_amdgcn_s_barrier();                       // B1: maxes final

        float rq[4];
        #pragma unroll
        for (int reg = 0; reg < 4; reg++) {
            const float mm = fmaxf(__int_as_float(shmax[wb][lq * 4 + reg]), 1e-12f);
            rq[reg] = 127.f / mm;
        }
        if (tid < 16) {
            shsc[wb][tid] = fmaxf(__int_as_float(shmax[wb][tid]), 1e-12f) * (1.f / 127.f);
            shmax[rb][tid] = 0;                             // recycle for t+1
        }
        #pragma unroll
        for (int reg = 0; reg < 4; reg++) {
            const int b = lq * 4 + reg;
            #pragma unroll
            for (int rr = 0; rr < 2; rr++) {
                const int q = clamp127((int)rintf(hv[reg][rr] * rq[reg]));
                const int r = wv * 32 + rr * 16 + lo;
                Ab[wb][b * 256 + ((((r >> 4) ^ b) & 15) << 4) + (r & 15)] = (char)(int8_t)q;
            }
        }

        asm volatile("s_waitcnt lgkmcnt(0)" ::: "memory");
        __builtin_amdgcn_s_barrier();                       // B2: h(t+1 input) ready
    }
}

// ======================= post: fc over h history =======================
// grid = B*T/64 blocks x 256 thr; block handles 64 (b,t) rows; fw in regs.
__global__ __launch_bounds__(256) void fc_out(
    const uint32_t* __restrict__ hist, const float* __restrict__ fcw,
    const float* __restrict__ fcb, float* __restrict__ out)
{
    const int tid = threadIdx.x;
    const int o_ = tid >> 3, ks = tid & 7;
    h2_t fw[16];
    {
        const float* fr = fcw + o_ * H_ + ks * 32;
        #pragma unroll
        for (int i = 0; i < 16; i++) {
            h2_t p; p[0] = (_Float16)fr[2 * i]; p[1] = (_Float16)fr[2 * i + 1];
            fw[i] = p;
        }
    }
    const float fcbv = fcb[o_];
    const size_t base = (size_t)blockIdx.x * 64;
    for (int i = 0; i < 64; i++) {
        const size_t ro = base + i;
        const v4u* hp = (const v4u*)(hist + ro * 128 + ks * 16);
        v4u fh[4];
        #pragma unroll
        for (int k = 0; k < 4; k++) fh[k] = hp[k];
        float acc = 0.f;
        #pragma unroll
        for (int k = 0; k < 16; k++) {
            union { uint32_t u; h2_t h; } z;
            z.u = fh[k >> 2][k & 3];
            acc = fdot2h(fw[k], z.h, acc);
        }
        acc = sum8(acc);
        if (ks == 7) out[ro * 32 + o_] = acc + fcbv;
    }
}

// ======================= fallback (round-6, verified) =======================
__global__ __launch_bounds__(64) void prep_w_fb(
    const float* __restrict__ Whh, const float* __restrict__ Wih,
    const float* __restrict__ bih, const float* __restrict__ bhh,
    uint32_t* __restrict__ qw4, uint32_t* __restrict__ wih4,
    float* __restrict__ s1v, float* __restrict__ biasv)
{
    const int gr = blockIdx.x;
    const int c  = threadIdx.x;
    const int j  = gr >> 8;
    const int r  = gr & 255;

    const float4 wv = ((const float4*)(Whh + gr * H_))[c];
    float m = fmaxf(fmaxf(fabsf(wv.x), fabsf(wv.y)), fmaxf(fabsf(wv.z), fabsf(wv.w)));
    #pragma unroll
    for (int s = 1; s < 64; s <<= 1) m = fmaxf(m, __shfl_xor(m, s, 64));
    const float S1 = fmaxf(m, 1e-20f) / 127.f;
    const float r1 = 1.f / S1;
    {
        const int d = j * 64 + c;
        qw4[(d >> 2) * 1024 + r * 4 + (d & 3)] = pack_q(
            clamp127((int)rintf(wv.x * r1)), clamp127((int)rintf(wv.y * r1)),
            clamp127((int)rintf(wv.z * r1)), clamp127((int)rintf(wv.w * r1)));
    }
    if (c < 16) {
        union { uint32_t u; h2_t h; } z;
        z.h[0] = (_Float16)Wih[gr * I_ + 2 * c];
        z.h[1] = (_Float16)Wih[gr * I_ + 2 * c + 1];
        const int dd = j * 16 + c;
        wih4[(dd >> 2) * 1024 + r * 4 + (dd & 3)] = z.u;
    }
    if (c == 0) { s1v[gr] = S1; biasv[gr] = bih[gr] + bhh[gr]; }
}

__global__ __launch_bounds__(256, 1) void lstm_fb(
    const uint32_t* __restrict__ qw4, const uint32_t* __restrict__ wih4,
    const float* __restrict__ s1v, const float* __restrict__ biasv,
    const uint32_t* __restrict__ xh, const float* __restrict__ fcw,
    const float* __restrict__ fcb, float* __restrict__ out)
{
    const int b  = blockIdx.x;
    const int r  = threadIdx.x;
    const int ln = r & 63;
    const int wv = r >> 6;

    __shared__ uint32_t hqb[2][64];
    __shared__ __align__(16) float hscb[2][4];
    __shared__ uint32_t hfb[2][128];

    v4u w4[64];
    #pragma unroll
    for (int d4 = 0; d4 < 64; d4++) w4[d4] = ((const v4u*)qw4)[d4 * 256 + r];
    v4u wx[16];
    #pragma unroll
    for (int d4 = 0; d4 < 16; d4++) wx[d4] = ((const v4u*)wih4)[d4 * 256 + r];
    float S1j[4], bj[4];
    #pragma unroll
    for (int j = 0; j < 4; j++) { S1j[j] = s1v[j * 256 + r]; bj[j] = biasv[j * 256 + r]; }

    const int o_ = r >> 3, ks = r & 7;
    h2_t fw[16];
    {
        const float* fr = fcw + o_ * H_ + ks * 32;
        #pragma unroll
        for (int i = 0; i < 16; i++) {
            h2_t p; p[0] = (_Float16)fr[2 * i]; p[1] = (_Float16)fr[2 * i + 1];
            fw[i] = p;
        }
    }
    const float fcb_v = fcb[o_];

    if (r < 4) hscb[1][r] = 0.f;
    __syncthreads();

    const uint32_t* xb   = xh + (size_t)(b * T_) * 16;
    float*          outb = out + (size_t)(b * T_) * O_;

    float c_state = 0.f;

    for (int t = 0; t < T_; t++) {
        const int pb = (t & 1) ^ 1, cb = t & 1;

        const v4u* xv = (const v4u*)(xb + (size_t)t * 16);
        const v4u x0 = xv[0], x1 = xv[1], x2 = xv[2], x3 = xv[3];

        const v4u*   hqv = (const v4u*)&hqb[pb][0];
        const float4 scv = *(const float4*)&hscb[pb][0];
        const float  scar[4] = { scv.x, scv.y, scv.z, scv.w };

        float a0 = 0.f, a1 = 0.f, a2 = 0.f, a3 = 0.f;
        #pragma unroll
        for (int g = 0; g < 4; g++) {
            v4u hg[4];
            #pragma unroll
            for (int q = 0; q < 4; q++) hg[q] = hqv[g * 4 + q];
            int i0 = 0, i1 = 0, i2 = 0, i3 = 0;
            #pragma unroll
            for (int q = 0; q < 4; q++) {
                #pragma unroll
                for (int e = 0; e < 4; e++) {
                    const int hvv = (int)hg[q][e];
                    i0 = dot4((int)w4[ 0 + g * 4 + q][e], hvv, i0);
                    i1 = dot4((int)w4[16 + g * 4 + q][e], hvv, i1);
                    i2 = dot4((int)w4[32 + g * 4 + q][e], hvv, i2);
                    i3 = dot4((int)w4[48 + g * 4 + q][e], hvv, i3);
                }
            }
            a0 = fmaf((float)i0, scar[g], a0);
            a1 = fmaf((float)i1, scar[g], a1);
            a2 = fmaf((float)i2, scar[g], a2);
            a3 = fmaf((float)i3, scar[g], a3);
        }

        if (t > 0) {
            const v4u* hfv = (const v4u*)&hfb[pb][0];
            v4u fh[4];
            #pragma unroll
            for (int i = 0; i < 4; i++) fh[i] = hfv[ks * 4 + i];
            float acc = 0.f;
            #pragma unroll
            for (int i = 0; i < 16; i++) {
                union { uint32_t u; h2_t h; } z;
                z.u = fh[i >> 2][i & 3];
                acc = fdot2h(fw[i], z.h, acc);
            }
            acc = sum8(acc);
            if (ks == 7) outb[(t - 1) * O_ + o_] = acc + fcb_v;
        }

        float xd0 = 0.f, xd1 = 0.f, xd2 = 0.f, xd3 = 0.f;
        {
            const v4u xg4[4] = { x0, x1, x2, x3 };
            #pragma unroll
            for (int d4 = 0; d4 < 4; d4++) {
                #pragma unroll
                for (int e = 0; e < 4; e++) {
                    union { uint32_t u; h2_t h; } zx, z0, z1, z2, z3;
                    zx.u = xg4[d4][e];
                    z0.u = wx[ 0 + d4][e]; xd0 = fdot2h(z0.h, zx.h, xd0);
                    z1.u = wx[ 4 + d4][e]; xd1 = fdot2h(z1.h, zx.h, xd1);
                    z2.u = wx[ 8 + d4][e]; xd2 = fdot2h(z2.h, zx.h, xd2);
                    z3.u = wx[12 + d4][e]; xd3 = fdot2h(z3.h, zx.h, xd3);
                }
            }
        }

        const float g0 = fmaf(a0, S1j[0], xd0 + bj[0]);
        const float g1 = fmaf(a1, S1j[1], xd1 + bj[1]);
        const float g2 = fmaf(a2, S1j[2], xd2 + bj[2]);
        const float g3 = fmaf(a3, S1j[3], xd3 + bj[3]);
        const float i_ = 1.f / (1.f + __expf(-g0));
        const float f_ = 1.f / (1.f + __expf(-g1));
        const float gg = 2.f / (1.f + __expf(-2.f * g2)) - 1.f;
        const float oo = 1.f / (1.f + __expf(-g3));
        c_state = f_ * c_state + i_ * gg;
        const float tc = 2.f / (1.f + __expf(-2.f * c_state)) - 1.f;
        const float hval = oo * tc;

        float m = wave64_max_bcast(fabsf(hval));
        m = fmaxf(m, 1e-12f);
        const int q = clamp127((int)rintf(hval * (127.f / m)));
        ((char*)&hqb[cb][0])[r] = (char)(int8_t)q;
        if (ln == 0) hscb[cb][wv] = m * (1.f / 127.f);
        ((_Float16*)&hfb[cb][0])[r] = (_Float16)hval;

        asm volatile("s_waitcnt lgkmcnt(0)" ::: "memory");
        __builtin_amdgcn_s_barrier();
    }

    {
        const int pb = (T_ - 1) & 1;
        const v4u* hfv = (const v4u*)&hfb[pb][0];
        v4u fh[4];
        #pragma unroll
        for (int i = 0; i < 4; i++) fh[i] = hfv[ks * 4 + i];
        float acc = 0.f;
        #pragma unroll
        for (int i = 0; i < 16; i++) {
            union { uint32_t u; h2_t h; } z;
            z.u = fh[i >> 2][i & 3];
            acc = fdot2h(fw[i], z.h, acc);
        }
        acc = sum8(acc);
        if (ks == 7) outb[(T_ - 1) * O_ + o_] = acc + fcb_v;
    }
}

// ======================= launch =======================
extern "C" void kernel_launch(void* const* d_in, const int* in_sizes, int n_in,
                              void* d_out, int out_size, void* d_ws, size_t ws_size,
                              hipStream_t stream) {
    const float* x    = (const float*)d_in[0];
    const float* Wih  = (const float*)d_in[1];
    const float* Whh  = (const float*)d_in[2];
    const float* bih  = (const float*)d_in[3];
    const float* bhh  = (const float*)d_in[4];
    const float* fcw  = (const float*)d_in[5];
    const float* fcb  = (const float*)d_in[6];
    float* out = (float*)d_out;

    char* ws = (char*)d_ws;
    uint32_t* xh = (uint32_t*)(ws + XH_OFF);

    if (ws_size >= WS_NEED) {
        uint32_t*  wq    = (uint32_t*)(ws + WQ_OFF);
        float*     s1p   = (float*)(ws + S1_OFF);
        float*     biasp = (float*)(ws + BIAS_OFF);
        uint32_t*  wihh  = (uint32_t*)(ws + WIHH_OFF);
        uint32_t*  xga   = (uint32_t*)(ws + XGA_OFF);
        _Float16*  hist  = (_Float16*)(ws + HIST_OFF);

        prep_wq<<<1024, 64, 0, stream>>>(Whh, Wih, bih, bhh, wq, s1p, biasp, wihh);
        prep_xh<<<(B_ * T_ * 16) / 256, 256, 0, stream>>>(x, xh);
        prep_xg<<<NBLK * T_, 512, 0, stream>>>(xh, wihh, biasp, xga);
        lstm_mfma<<<NBLK, 512, 0, stream>>>(wq, s1p, xga, hist);
        fc_out<<<(B_ * T_) / 64, 256, 0, stream>>>((const uint32_t*)hist, fcw, fcb, out);
    } else {
        uint32_t* qw4   = (uint32_t*)(ws + FQW_OFF);
        uint32_t* wih4  = (uint32_t*)(ws + FWIH_OFF);
        float*    s1v   = (float*)(ws + FS1_OFF);
        float*    biasv = (float*)(ws + FBIAS_OFF);

        prep_w_fb<<<1024, 64, 0, stream>>>(Whh, Wih, bih, bhh, qw4, wih4, s1v, biasv);
        prep_xh<<<(B_ * T_ * 16) / 256, 256, 0, stream>>>(x, xh);
        lstm_fb<<<B_, 256, 0, stream>>>(qw4, wih4, s1v, biasv, xh, fcw, fcb, out);
    }
}